// Round 15
// baseline (87.191 us; speedup 1.0000x reference)
//
#include <hip/hip_runtime.h>
#include <math.h>

#define HEADS 8
#define NTOK  2304
#define DH    64
#define QD    320
#define INNER 512
#define NSPLIT 6
#define TPS   12     // 32-key tiles per split (72 total, 6 splits)

typedef _Float16 f16;
typedef f16  f16x4 __attribute__((ext_vector_type(4)));
typedef f16  f16x8 __attribute__((ext_vector_type(8)));
typedef float f32x4 __attribute__((ext_vector_type(4)));

#define MFMA(a,b,c) __builtin_amdgcn_mfma_f32_16x16x32_f16((a),(b),(c),0,0,0)

#define GLDS(gp, lp) __builtin_amdgcn_global_load_lds(                      \
    (const __attribute__((address_space(1))) void*)(gp),                    \
    (__attribute__((address_space(3))) void*)(lp), 16, 0, 0)

#if __has_builtin(__builtin_amdgcn_exp2f)
#define EXP2(x) __builtin_amdgcn_exp2f(x)
#else
#define EXP2(x) exp2f(x)
#endif

#define LOG2E 1.44269504f

static __device__ __forceinline__ unsigned pkrtz(float a, float b) {
#if __has_builtin(__builtin_amdgcn_cvt_pkrtz)
  return __builtin_bit_cast(unsigned, __builtin_amdgcn_cvt_pkrtz(a, b));
#else
  union { f16 h[2]; unsigned u; } c;
  c.h[0] = (f16)a; c.h[1] = (f16)b;
  return c.u;
#endif
}

// ---------------------------------------------------------------------------
// prep_all: fused prep + qblend.
//   [0,1728):    f32->f16 cvt: qinj->qc16(x1), kinj->k16(x1), kcnt->kc16(x0.125*log2e)
//   [1728,2304): v/vcnt -> f16 transposed [h][d][n]
//   [2304,2344): Wo -> WoT f16
//   [2344,2920): qblend: qhat = (qinj + x@Wq)*0.09375*log2e  (self-contained:
//                x fp32 A-frags converted in-register; Wq chunk LDS-transposed)
// ---------------------------------------------------------------------------
__global__ __launch_bounds__(256) void prep_all(
    const float* __restrict__ qi, const float* __restrict__ ki,
    const float* __restrict__ kc, const float* __restrict__ x,
    const float* __restrict__ v,  const float* __restrict__ vc,
    const float* __restrict__ Wq, const float* __restrict__ Wo,
    f16* __restrict__ oq, f16* __restrict__ ok, f16* __restrict__ okc,
    f16* __restrict__ vt, f16* __restrict__ vct,
    f16* __restrict__ WoT, f16* __restrict__ qhat)
{
  __shared__ float T[64][65];
  __shared__ __align__(16) f16 qT[2][2560];   // [buf][64 cols][40]
  const int bid = blockIdx.x;
  const int tid = threadIdx.x;

  if (bid < 1728) {                       // ---- flat cvt (3 tensors) ----
    int i = bid * 256 + tid;
    const float* src; f16* dst; float s = 1.0f; int off;
    if (i < 147456)      { src = qi; dst = oq;  off = i; }
    else if (i < 294912) { src = ki; dst = ok;  off = i - 147456; }
    else                 { src = kc; dst = okc; off = i - 294912; s = 0.125f * LOG2E; }
    float4 a = reinterpret_cast<const float4*>(src)[off * 2];
    float4 b = reinterpret_cast<const float4*>(src)[off * 2 + 1];
    f16x8 o;
    o[0] = (f16)(a.x * s); o[1] = (f16)(a.y * s);
    o[2] = (f16)(a.z * s); o[3] = (f16)(a.w * s);
    o[4] = (f16)(b.x * s); o[5] = (f16)(b.y * s);
    o[6] = (f16)(b.z * s); o[7] = (f16)(b.w * s);
    *reinterpret_cast<f16x8*>(&dst[(size_t)off * 8]) = o;
  } else if (bid < 2304) {                // ---- V transpose ----
    int t = bid - 1728;
    int z = t / 288, rem = t % 288;
    int h = rem / 36, nt = rem % 36;
    const float* src = z ? vc : v;
    f16* dst = z ? vct : vt;
    const int n0 = nt * 64;
    const size_t base = ((size_t)h * NTOK + n0) * DH;
    for (int it = 0; it < 4; ++it) {
      int idx = tid + it * 256;
      int n = idx >> 4, d0 = (idx & 15) * 4;
      float4 a = *reinterpret_cast<const float4*>(&src[base + (size_t)n * DH + d0]);
      T[n][d0] = a.x; T[n][d0 + 1] = a.y; T[n][d0 + 2] = a.z; T[n][d0 + 3] = a.w;
    }
    __syncthreads();
    for (int it = 0; it < 2; ++it) {
      int idx = tid + it * 256;
      int d = idx >> 3, c0 = (idx & 7) * 8;
      f16x8 o;
      #pragma unroll
      for (int i = 0; i < 8; ++i) o[i] = (f16)T[c0 + i][d];
      *reinterpret_cast<f16x8*>(&dst[(size_t)(h * 64 + d) * NTOK + n0 + c0]) = o;
    }
  } else if (bid < 2344) {                // ---- Wo transpose ----
    int b2 = bid - 2304;
    const int R = INNER, C = QD;
    const int ctiles = C >> 6;            // 5
    const int rt = b2 / ctiles, ct = b2 % ctiles;
    for (int it = 0; it < 4; ++it) {
      int idx = tid + it * 256;
      int r = idx >> 4, c4 = (idx & 15) * 4;
      float4 a = *reinterpret_cast<const float4*>(&Wo[(size_t)(rt * 64 + r) * C + ct * 64 + c4]);
      T[r][c4] = a.x; T[r][c4 + 1] = a.y; T[r][c4 + 2] = a.z; T[r][c4 + 3] = a.w;
    }
    __syncthreads();
    for (int it = 0; it < 4; ++it) {
      int idx = tid + it * 256;
      int c = idx >> 4, r4 = (idx & 15) * 4;
      f16x4 o;
      #pragma unroll
      for (int i = 0; i < 4; ++i) o[i] = (f16)T[r4 + i][c];
      *reinterpret_cast<f16x4*>(&WoT[(size_t)(ct * 64 + c) * R + rt * 64 + r4]) = o;
    }
  } else {                                // ---- qblend (self-contained) ----
    int b = bid - 2344;
    int qt = b % 72, h = b / 72;
    const int n0 = qt * 32;
    const int w = tid >> 6, l = tid & 63, lq = l & 15, lk = l >> 4;
    const int qsub = w & 1, ch = w >> 1;
    const int kk = tid >> 3, c8 = (tid & 7) * 8;
    f32x4 acc[2] = {};
    {   // stage chunk 0: qT[0][c][kk] = Wq[kk][h*64+c]
      const float* wr = Wq + (size_t)kk * INNER + h * 64 + c8;
      float4 a0 = *reinterpret_cast<const float4*>(wr);
      float4 a1 = *reinterpret_cast<const float4*>(wr + 4);
      #pragma unroll
      for (int j = 0; j < 4; ++j) {
        qT[0][(c8 + j) * 40 + kk]     = (f16)(&a0.x)[j];
        qT[0][(c8 + 4 + j) * 40 + kk] = (f16)(&a1.x)[j];
      }
    }
    __syncthreads();
    #pragma unroll
    for (int ks = 0; ks < 10; ++ks) {
      if (ks + 1 < 10) {
        const float* wr = Wq + (size_t)((ks + 1) * 32 + kk) * INNER + h * 64 + c8;
        float4 a0 = *reinterpret_cast<const float4*>(wr);
        float4 a1 = *reinterpret_cast<const float4*>(wr + 4);
        #pragma unroll
        for (int j = 0; j < 4; ++j) {
          qT[(ks + 1) & 1][(c8 + j) * 40 + kk]     = (f16)(&a0.x)[j];
          qT[(ks + 1) & 1][(c8 + 4 + j) * 40 + kk] = (f16)(&a1.x)[j];
        }
      }
      const float* xr = x + (size_t)(n0 + qsub * 16 + lq) * QD + ks * 32 + lk * 8;
      float4 u0 = *reinterpret_cast<const float4*>(xr);
      float4 u1 = *reinterpret_cast<const float4*>(xr + 4);
      f16x8 af;
      af[0] = (f16)u0.x; af[1] = (f16)u0.y; af[2] = (f16)u0.z; af[3] = (f16)u0.w;
      af[4] = (f16)u1.x; af[5] = (f16)u1.y; af[6] = (f16)u1.z; af[7] = (f16)u1.w;
      const f16* bb = &qT[ks & 1][0];
      #pragma unroll
      for (int df = 0; df < 2; ++df) {
        f16x8 bf = *reinterpret_cast<const f16x8*>(
            &bb[(ch * 32 + df * 16 + lq) * 40 + lk * 8]);
        acc[df] = MFMA(af, bf, acc[df]);
      }
      __syncthreads();
    }
    const float scq = 0.09375f * LOG2E;
    #pragma unroll
    for (int df = 0; df < 2; ++df)
      #pragma unroll
      for (int r = 0; r < 4; ++r) {
        int n = n0 + qsub * 16 + lk * 4 + r;
        int d = ch * 32 + df * 16 + lq;
        size_t idx = ((size_t)h * NTOK + n) * DH + d;
        qhat[idx] = (f16)(scq * (qi[idx] + acc[df][r]));
      }
  }
}

// ---------------------------------------------------------------------------
// attn_f16p: R14's no-max split-K kernel at 6-way split (TPS=12).
// grid 2304 = 8h x 2strm x 6sp x 24qt -> 8 blocks/CU co-resident (LDS cap)
// = 16 waves/CU. Inner loop identical to R11/R14. f16 O partials.
// ---------------------------------------------------------------------------
__global__ __launch_bounds__(128, 2) void attn_f16p(
    const f16* __restrict__ qhat, const f16* __restrict__ qc16,
    const f16* __restrict__ k16,  const f16* __restrict__ kc16,
    const f16* __restrict__ vt16, const f16* __restrict__ vct16,
    f16* __restrict__ partO, float* __restrict__ partS)
{
  __shared__ __align__(16) f16 smem[2][2][2048];   // [buf][K|V][32x64 | 64x32]
  __shared__ __align__(16) f16 pbuf[2][640];       // per-wave P [16q][40]

  const int bid = blockIdx.x;
  const int h    = bid & 7;
  const int strm = (bid >> 3) & 1;
  const int r6   = bid >> 4;              // 0..143
  const int sp   = r6 % 6;
  const int qt   = r6 / 6;                // 0..23 (96 q-rows each)
  const int tid = threadIdx.x;
  const int w = tid >> 6, l = tid & 63;
  const int lq = l & 15, lk = l >> 4;
  const size_t hb = (size_t)h * NTOK * DH;
  const int row0 = qt * 96 + w * 48 + lq;   // qblock rows: +0, +16, +32

  // ---- Q fragments (B-operand, 16B contiguous per lane) ----
  f16x8 qh0[2], qh1[2], qh2[2], qc0[2], qc1[2], qc2[2];
  {
    const size_t qr0 = hb + (size_t)row0 * DH;
    #pragma unroll
    for (int ks = 0; ks < 2; ++ks) {
      const int o = ks * 32 + lk * 8;
      qc0[ks] = *reinterpret_cast<const f16x8*>(&qc16[qr0 + o]);
      qc1[ks] = *reinterpret_cast<const f16x8*>(&qc16[qr0 + 16 * DH + o]);
      qc2[ks] = *reinterpret_cast<const f16x8*>(&qc16[qr0 + 32 * DH + o]);
      if (!strm) {
        qh0[ks] = *reinterpret_cast<const f16x8*>(&qhat[qr0 + o]);
        qh1[ks] = *reinterpret_cast<const f16x8*>(&qhat[qr0 + 16 * DH + o]);
        qh2[ks] = *reinterpret_cast<const f16x8*>(&qhat[qr0 + 32 * DH + o]);
      } else { qh0[ks] = qc0[ks]; qh1[ks] = qc1[ks]; qh2[ks] = qc2[ks]; }
    }
  }

  // ---- staging geometry (linear dest + inverse-swizzled source for K) ----
  const int krow = tid >> 3;                       // 0..15 (chunk2: +16)
  const int ksw  = ((tid & 7) ^ (krow & 7)) * 8;
  const int vrow = tid >> 2;                       // 0..31 (chunk2: +32)
  const int voff = (tid & 3) * 8;
  const f16* gK = (strm ? kc16 : k16) + hb;
  const f16* gV = (strm ? vct16 : vt16) + (size_t)h * DH * NTOK;
  const int lb0 = __builtin_amdgcn_readfirstlane((tid & 64) * 8);
  const int lb1 = 1024 + lb0;

  #define STAGE(nb, j0)                                                      \
    do {                                                                     \
      GLDS(gK + (size_t)((j0) + krow) * 64 + ksw,        &smem[nb][0][lb0]); \
      GLDS(gK + (size_t)((j0) + 16 + krow) * 64 + ksw,   &smem[nb][0][lb1]); \
      GLDS(gV + (size_t)vrow * NTOK + (j0) + voff,       &smem[nb][1][lb0]); \
      GLDS(gV + (size_t)(32 + vrow) * NTOK + (j0) + voff,&smem[nb][1][lb1]); \
    } while (0)

  const int swz = (lq & 7) * 8;
  int xo[2];
  #pragma unroll
  for (int ks = 0; ks < 2; ++ks) xo[ks] = ((ks * 32 + lk * 8) ^ swz);

  float S0 = 0.f, S1 = 0.f, S2 = 0.f;            // per-lane exp-sums
  float ax0, ax1, ax2;                            // per-lane aux partials
  ax0 = ax1 = ax2 = strm ? INFINITY : -INFINITY;
  f32x4 O0[4] = {}, O1_[4] = {}, O2_[4] = {};
  f16* Pq = &pbuf[w][0];

  // no-max softmax: exp2 + per-lane sum + P round-trip -> PV B-fragment
  auto SMX = [&](const f32x4* s, float& Sl) -> f16x8 {
    float p0 = EXP2(s[0][0]), p1 = EXP2(s[0][1]);
    float p2 = EXP2(s[0][2]), p3 = EXP2(s[0][3]);
    float p4 = EXP2(s[1][0]), p5 = EXP2(s[1][1]);
    float p6 = EXP2(s[1][2]), p7 = EXP2(s[1][3]);
    Sl += ((p0 + p1) + (p2 + p3)) + ((p4 + p5) + (p6 + p7));
    uint2 wA, wB;
    wA.x = pkrtz(p0, p1); wA.y = pkrtz(p2, p3);
    wB.x = pkrtz(p4, p5); wB.y = pkrtz(p6, p7);
    *reinterpret_cast<uint2*>(Pq + lq * 40 + lk * 4)      = wA;  // keys jf0
    *reinterpret_cast<uint2*>(Pq + lq * 40 + 16 + lk * 4) = wB;  // keys jf1
    return *reinterpret_cast<const f16x8*>(Pq + lq * 40 + lk * 8);
  };

  const int jb = sp * (TPS * 32);
  STAGE(0, jb);
  asm volatile("s_waitcnt vmcnt(0)" ::: "memory");
  __builtin_amdgcn_sched_barrier(0);
  __builtin_amdgcn_s_barrier();
  __builtin_amdgcn_sched_barrier(0);

  int cur = 0;
  for (int t = 0; t < TPS; ++t) {
    if (t + 1 < TPS) STAGE(cur ^ 1, jb + (t + 1) * 32);

    const f16* Kb = &smem[cur][0][0];
    const f16* Vb = &smem[cur][1][0];

    // ---- QK^T (swapped): s[key][q], 3 qblocks share every K read ----
    f32x4 sA[2] = {}, sB[2] = {}, sC[2] = {};
    __builtin_amdgcn_s_setprio(1);
    if (!strm) {
      float m3A = -INFINITY, m3B = -INFINITY, m3C = -INFINITY;
      #pragma unroll
      for (int jf = 0; jf < 2; ++jf) {
        f32x4 tA = {}, tB = {}, tC = {};
        const int rb = (jf * 16 + lq) * 64;
        #pragma unroll
        for (int ks = 0; ks < 2; ++ks) {
          f16x8 aK = *reinterpret_cast<const f16x8*>(&Kb[rb + xo[ks]]);
          sA[jf] = MFMA(aK, qh0[ks], sA[jf]);
          sB[jf] = MFMA(aK, qh1[ks], sB[jf]);
          sC[jf] = MFMA(aK, qh2[ks], sC[jf]);
          tA = MFMA(aK, qc0[ks], tA);
          tB = MFMA(aK, qc1[ks], tB);
          tC = MFMA(aK, qc2[ks], tC);
        }
        m3A = fmaxf(m3A, fmaxf(fmaxf(tA[0], tA[1]), fmaxf(tA[2], tA[3])));
        m3B = fmaxf(m3B, fmaxf(fmaxf(tB[0], tB[1]), fmaxf(tB[2], tB[3])));
        m3C = fmaxf(m3C, fmaxf(fmaxf(tC[0], tC[1]), fmaxf(tC[2], tC[3])));
      }
      ax0 = fmaxf(ax0, m3A); ax1 = fmaxf(ax1, m3B); ax2 = fmaxf(ax2, m3C);
    } else {
      #pragma unroll
      for (int jf = 0; jf < 2; ++jf) {
        const int rb = (jf * 16 + lq) * 64;
        #pragma unroll
        for (int ks = 0; ks < 2; ++ks) {
          f16x8 aK = *reinterpret_cast<const f16x8*>(&Kb[rb + xo[ks]]);
          sA[jf] = MFMA(aK, qc0[ks], sA[jf]);
          sB[jf] = MFMA(aK, qc1[ks], sB[jf]);
          sC[jf] = MFMA(aK, qc2[ks], sC[jf]);
        }
      }
      ax0 = fminf(ax0, fminf(fminf(fminf(sA[0][0], sA[0][1]), fminf(sA[0][2], sA[0][3])),
                             fminf(fminf(sA[1][0], sA[1][1]), fminf(sA[1][2], sA[1][3]))));
      ax1 = fminf(ax1, fminf(fminf(fminf(sB[0][0], sB[0][1]), fminf(sB[0][2], sB[0][3])),
                             fminf(fminf(sB[1][0], sB[1][1]), fminf(sB[1][2], sB[1][3]))));
      ax2 = fminf(ax2, fminf(fminf(fminf(sC[0][0], sC[0][1]), fminf(sC[0][2], sC[0][3])),
                             fminf(fminf(sC[1][0], sC[1][1]), fminf(sC[1][2], sC[1][3]))));
    }
    __builtin_amdgcn_s_setprio(0);

    // ---- no-max softmax + P round-trip (no shfl, no rescale) ----
    f16x8 pbA = SMX(sA, S0);
    f16x8 pbB = SMX(sB, S1);
    f16x8 pbC = SMX(sC, S2);

    // ---- PV (swapped): O[d][q], 3 qblocks share every V read ----
    __builtin_amdgcn_s_setprio(1);
    #pragma unroll
    for (int df = 0; df < 4; ++df) {
      f16x8 aV = *reinterpret_cast<const f16x8*>(&Vb[(df * 16 + lq) * 32 + lk * 8]);
      O0[df]  = MFMA(aV, pbA, O0[df]);
      O1_[df] = MFMA(aV, pbB, O1_[df]);
      O2_[df] = MFMA(aV, pbC, O2_[df]);
    }
    __builtin_amdgcn_s_setprio(0);

    asm volatile("s_waitcnt vmcnt(0)" ::: "memory");
    __builtin_amdgcn_sched_barrier(0);
    __builtin_amdgcn_s_barrier();
    __builtin_amdgcn_sched_barrier(0);
    cur ^= 1;
  }

  // ---- final per-lane -> per-row reductions, then f16 partial store ----
  S0 += __shfl_xor(S0, 16); S0 += __shfl_xor(S0, 32);
  S1 += __shfl_xor(S1, 16); S1 += __shfl_xor(S1, 32);
  S2 += __shfl_xor(S2, 16); S2 += __shfl_xor(S2, 32);
  if (!strm) {
    ax0 = fmaxf(ax0, __shfl_xor(ax0, 16)); ax0 = fmaxf(ax0, __shfl_xor(ax0, 32));
    ax1 = fmaxf(ax1, __shfl_xor(ax1, 16)); ax1 = fmaxf(ax1, __shfl_xor(ax1, 32));
    ax2 = fmaxf(ax2, __shfl_xor(ax2, 16)); ax2 = fmaxf(ax2, __shfl_xor(ax2, 32));
  } else {
    ax0 = fminf(ax0, __shfl_xor(ax0, 16)); ax0 = fminf(ax0, __shfl_xor(ax0, 32));
    ax1 = fminf(ax1, __shfl_xor(ax1, 16)); ax1 = fminf(ax1, __shfl_xor(ax1, 32));
    ax2 = fminf(ax2, __shfl_xor(ax2, 16)); ax2 = fminf(ax2, __shfl_xor(ax2, 32));
  }
  {
    const size_t u = (size_t)((strm * NSPLIT + sp) * 8 + h);
    f16* p0 = partO + (u * NTOK + (size_t)row0) * 64;
    f16* p1 = p0 + (size_t)16 * 64;
    f16* p2 = p0 + (size_t)32 * 64;
    #pragma unroll
    for (int df = 0; df < 4; ++df) {
      uint2 w0, w1, w2;
      w0.x = pkrtz(O0[df][0],  O0[df][1]);  w0.y = pkrtz(O0[df][2],  O0[df][3]);
      w1.x = pkrtz(O1_[df][0], O1_[df][1]); w1.y = pkrtz(O1_[df][2], O1_[df][3]);
      w2.x = pkrtz(O2_[df][0], O2_[df][1]); w2.y = pkrtz(O2_[df][2], O2_[df][3]);
      *reinterpret_cast<uint2*>(p0 + df * 16 + lk * 4) = w0;
      *reinterpret_cast<uint2*>(p1 + df * 16 + lk * 4) = w1;
      *reinterpret_cast<uint2*>(p2 + df * 16 + lk * 4) = w2;
    }
    if (lk == 0) {
      float* s0 = partS + (u * NTOK + (size_t)row0) * 2;
      s0[0] = S0; s0[1] = ax0;
      s0[32] = S1; s0[33] = ax1;     // row0+16
      s0[64] = S2; s0[65] = ax2;     // row0+32
    }
  }
  #undef STAGE
}

// ---------------------------------------------------------------------------
// merge6: sum 6 splits x 2 streams (f16 O partials, linear), gvm, write mid.
// grid 288 (1D, h = bid&7 pins merge of head h to attn's XCD): 256 thr =
// (row 0..63) x (16-d segment 0..3).
// ---------------------------------------------------------------------------
__global__ __launch_bounds__(256) void merge6(
    const f16* __restrict__ partO, const float* __restrict__ partS,
    const float* __restrict__ mask, f16* __restrict__ mid)
{
  const int h = blockIdx.x & 7, qt = blockIdx.x >> 3;
  const int tid = threadIdx.x;
  const int r = tid >> 2, ds = (tid & 3) * 16;
  const int n = qt * 64 + r;

  float S1 = 0.f, S2 = 0.f, mx = -INFINITY, mn = INFINITY;
  #pragma unroll
  for (int s = 0; s < NSPLIT; ++s) {
    const float* a = partS + ((size_t)((0 * NSPLIT + s) * 8 + h) * NTOK + n) * 2;
    const float* b = partS + ((size_t)((1 * NSPLIT + s) * 8 + h) * NTOK + n) * 2;
    S1 += a[0]; mx = fmaxf(mx, a[1]);
    S2 += b[0]; mn = fminf(mn, b[1]);
  }

  float mv = mask[n];
  float mm = (mv < 0.5f) ? 1.0f : (mv > 0.5f ? -1.0f : -mv);
  float gvm = (mn - mx * LOG2E) * mm;          // exp2 domain
  float A1 = gvm;
  float Mf = fmaxf(A1, 0.0f);
  float w1 = exp2f(A1 - Mf), w2 = exp2f(-Mf);
  float inv = 1.0f / (w1 * S1 + w2 * S2);

  float o1[16] = {}, o2[16] = {};
  #pragma unroll
  for (int s = 0; s < NSPLIT; ++s) {
    const f16* a = partO + ((size_t)((0 * NSPLIT + s) * 8 + h) * NTOK + n) * 64 + ds;
    const f16* b = partO + ((size_t)((1 * NSPLIT + s) * 8 + h) * NTOK + n) * 64 + ds;
    f16x8 a0 = *reinterpret_cast<const f16x8*>(a);
    f16x8 a1 = *reinterpret_cast<const f16x8*>(a + 8);
    f16x8 b0 = *reinterpret_cast<const f16x8*>(b);
    f16x8 b1 = *reinterpret_cast<const f16x8*>(b + 8);
    #pragma unroll
    for (int j = 0; j < 8; ++j) {
      o1[j]     += (float)a0[j];
      o1[8 + j] += (float)a1[j];
      o2[j]     += (float)b0[j];
      o2[8 + j] += (float)b1[j];
    }
  }
  f16 ov[16];
  #pragma unroll
  for (int j = 0; j < 16; ++j)
    ov[j] = (f16)((w1 * o1[j] + w2 * o2[j]) * inv);
  f16* dst = mid + (size_t)n * INNER + h * 64 + ds;
  *reinterpret_cast<f16x8*>(dst)     = *reinterpret_cast<f16x8*>(&ov[0]);
  *reinterpret_cast<f16x8*>(dst + 8) = *reinterpret_cast<f16x8*>(&ov[8]);
}

// ---------------------------------------------------------------------------
// out_mfma: out = mid(f16) @ Wo + bo.  grid (144, 5), 64 threads (1 wave).
// ---------------------------------------------------------------------------
__global__ __launch_bounds__(64) void out_mfma(
    const f16* __restrict__ mid, const f16* __restrict__ WoT,
    const float* __restrict__ bo, float* __restrict__ out)
{
  const int n0 = blockIdx.x * 16;
  const int o0 = blockIdx.y * 64;
  const int l = threadIdx.x, lq = l & 15, lk = l >> 4;
  f32x4 acc[4] = {};
  const f16* arow = mid + (size_t)(n0 + lq) * INNER;
  #pragma unroll
  for (int ks = 0; ks < 16; ++ks) {
    f16x8 a = *reinterpret_cast<const f16x8*>(&arow[ks * 32 + lk * 8]);
    #pragma unroll
    for (int df = 0; df < 4; ++df) {
      f16x8 b = *reinterpret_cast<const f16x8*>(
          &WoT[(size_t)(o0 + df * 16 + lq) * INNER + ks * 32 + lk * 8]);
      acc[df] = MFMA(a, b, acc[df]);
    }
  }
  #pragma unroll
  for (int df = 0; df < 4; ++df) {
    float bb = bo[o0 + df * 16 + lq];
    #pragma unroll
    for (int r = 0; r < 4; ++r) {
      int n = n0 + lk * 4 + r;
      out[(size_t)n * QD + o0 + df * 16 + lq] = acc[df][r] + bb;
    }
  }
}

// ---------------------------------------------------------------------------
extern "C" void kernel_launch(void* const* d_in, const int* in_sizes, int n_in,
                              void* d_out, int out_size, void* d_ws, size_t ws_size,
                              hipStream_t stream) {
  const float* x    = (const float*)d_in[0];
  const float* Wq   = (const float*)d_in[1];
  const float* Wo   = (const float*)d_in[2];
  const float* bo   = (const float*)d_in[3];
  const float* qinj = (const float*)d_in[4];
  const float* kinj = (const float*)d_in[5];
  const float* vinj = (const float*)d_in[6];
  const float* kcnt = (const float*)d_in[7];
  const float* vcnt = (const float*)d_in[8];
  const float* mask = (const float*)d_in[9];
  float* out = (float*)d_out;

  const size_t T = (size_t)HEADS * NTOK * DH;   // 1179648
  f16* qhat = (f16*)d_ws;
  f16* qc16 = qhat + T;
  f16* k16  = qc16 + T;
  f16* kc16 = k16  + T;
  f16* vt16 = kc16 + T;
  f16* vct16= vt16 + T;
  f16* mid  = vct16 + T;                 // [2304][512] f16
  f16* WoT  = mid + T;
  f16* partO = WoT + 163840;             // 96u x 2304 x 64 f16 (~28 MB)
  float* partS = (float*)(partO + (size_t)96 * NTOK * 64);  // 96u x 2304 x 2 f32

  prep_all  <<<2920, 256, 0, stream>>>(qinj, kinj, kcnt, x, vinj, vcnt, Wq, Wo,
                                       qc16, k16, kc16, vt16, vct16, WoT, qhat);
  attn_f16p <<<2304, 128, 0, stream>>>(qhat, qc16, k16, kc16, vt16, vct16,
                                       partO, partS);
  merge6    <<<288, 256, 0, stream>>>(partO, partS, mask, mid);
  out_mfma  <<<dim3(144, 5), 64, 0, stream>>>(mid, WoT, bo, out);
}

// Round 16
// 78.605 us; speedup vs baseline: 1.1092x; 1.1092x over previous
//
#include <hip/hip_runtime.h>
#include <math.h>

#define HEADS 8
#define NTOK  2304
#define DH    64
#define QD    320
#define INNER 512
#define NSPLIT 4
#define TPS   18     // 32-key tiles per split (72 total, 4 splits)

typedef _Float16 f16;
typedef f16  f16x4 __attribute__((ext_vector_type(4)));
typedef f16  f16x8 __attribute__((ext_vector_type(8)));
typedef float f32x4 __attribute__((ext_vector_type(4)));

#define MFMA(a,b,c) __builtin_amdgcn_mfma_f32_16x16x32_f16((a),(b),(c),0,0,0)

#define GLDS(gp, lp) __builtin_amdgcn_global_load_lds(                      \
    (const __attribute__((address_space(1))) void*)(gp),                    \
    (__attribute__((address_space(3))) void*)(lp), 16, 0, 0)

#if __has_builtin(__builtin_amdgcn_exp2f)
#define EXP2(x) __builtin_amdgcn_exp2f(x)
#else
#define EXP2(x) exp2f(x)
#endif

#define LOG2E 1.44269504f

static __device__ __forceinline__ unsigned pkrtz(float a, float b) {
#if __has_builtin(__builtin_amdgcn_cvt_pkrtz)
  return __builtin_bit_cast(unsigned, __builtin_amdgcn_cvt_pkrtz(a, b));
#else
  union { f16 h[2]; unsigned u; } c;
  c.h[0] = (f16)a; c.h[1] = (f16)b;
  return c.u;
#endif
}

// ---------------------------------------------------------------------------
// prep_all: fused prep (identical to R14).
// ---------------------------------------------------------------------------
__global__ __launch_bounds__(256) void prep_all(
    const float* __restrict__ qi, const float* __restrict__ ki,
    const float* __restrict__ kc, const float* __restrict__ x,
    const float* __restrict__ v,  const float* __restrict__ vc,
    const float* __restrict__ Wq, const float* __restrict__ Wo,
    f16* __restrict__ oq, f16* __restrict__ ok, f16* __restrict__ okc,
    f16* __restrict__ ox, f16* __restrict__ vt, f16* __restrict__ vct,
    f16* __restrict__ WqT, f16* __restrict__ WoT)
{
  __shared__ float T[64][65];
  const int bid = blockIdx.x;
  const int tid = threadIdx.x;

  if (bid < 2088) {                       // ---- flat cvt ----
    int i = bid * 256 + tid;
    const float* src; f16* dst; float s = 1.0f; int off;
    if (i < 147456)      { src = qi; dst = oq;  off = i; }
    else if (i < 294912) { src = ki; dst = ok;  off = i - 147456; }
    else if (i < 442368) { src = kc; dst = okc; off = i - 294912; s = 0.125f * LOG2E; }
    else                 { src = x;  dst = ox;  off = i - 442368; }
    float4 a = reinterpret_cast<const float4*>(src)[off * 2];
    float4 b = reinterpret_cast<const float4*>(src)[off * 2 + 1];
    f16x8 o;
    o[0] = (f16)(a.x * s); o[1] = (f16)(a.y * s);
    o[2] = (f16)(a.z * s); o[3] = (f16)(a.w * s);
    o[4] = (f16)(b.x * s); o[5] = (f16)(b.y * s);
    o[6] = (f16)(b.z * s); o[7] = (f16)(b.w * s);
    *reinterpret_cast<f16x8*>(&dst[(size_t)off * 8]) = o;
  } else if (bid < 2664) {                // ---- V transpose ----
    int t = bid - 2088;
    int z = t / 288, rem = t % 288;
    int h = rem / 36, nt = rem % 36;
    const float* src = z ? vc : v;
    f16* dst = z ? vct : vt;
    const int n0 = nt * 64;
    const size_t base = ((size_t)h * NTOK + n0) * DH;
    for (int it = 0; it < 4; ++it) {
      int idx = tid + it * 256;
      int n = idx >> 4, d0 = (idx & 15) * 4;
      float4 a = *reinterpret_cast<const float4*>(&src[base + (size_t)n * DH + d0]);
      T[n][d0] = a.x; T[n][d0 + 1] = a.y; T[n][d0 + 2] = a.z; T[n][d0 + 3] = a.w;
    }
    __syncthreads();
    for (int it = 0; it < 2; ++it) {
      int idx = tid + it * 256;
      int d = idx >> 3, c0 = (idx & 7) * 8;
      f16x8 o;
      #pragma unroll
      for (int i = 0; i < 8; ++i) o[i] = (f16)T[c0 + i][d];
      *reinterpret_cast<f16x8*>(&dst[(size_t)(h * 64 + d) * NTOK + n0 + c0]) = o;
    }
  } else {                                // ---- weight transpose ----
    int t = bid - 2664;
    int z = t / 40, b = t % 40;
    const float* src = z ? Wo : Wq;
    f16* dst = z ? WoT : WqT;
    const int R = z ? INNER : QD;
    const int C = z ? QD : INNER;
    const int ctiles = C >> 6;
    const int rt = b / ctiles, ct = b % ctiles;
    for (int it = 0; it < 4; ++it) {
      int idx = tid + it * 256;
      int r = idx >> 4, c4 = (idx & 15) * 4;
      float4 a = *reinterpret_cast<const float4*>(&src[(size_t)(rt * 64 + r) * C + ct * 64 + c4]);
      T[r][c4] = a.x; T[r][c4 + 1] = a.y; T[r][c4 + 2] = a.z; T[r][c4 + 3] = a.w;
    }
    __syncthreads();
    for (int it = 0; it < 4; ++it) {
      int idx = tid + it * 256;
      int c = idx >> 4, r4 = (idx & 15) * 4;
      f16x4 o;
      #pragma unroll
      for (int i = 0; i < 4; ++i) o[i] = (f16)T[r4 + i][c];
      *reinterpret_cast<f16x4*>(&dst[(size_t)(ct * 64 + c) * R + rt * 64 + r4]) = o;
    }
  }
}

// ---------------------------------------------------------------------------
// qblend_mfma: qhat = (qinj + x@Wq) * 0.09375 * log2e  (identical to R14)
// ---------------------------------------------------------------------------
__global__ __launch_bounds__(256) void qblend_mfma(
    const f16* __restrict__ x16, const f16* __restrict__ WqT,
    const float* __restrict__ qinj, f16* __restrict__ qhat)
{
  const int qt = blockIdx.x, h = blockIdx.y;
  const int n0 = qt * 32;
  const int tid = threadIdx.x;
  const int w = tid >> 6, l = tid & 63, lq = l & 15, lk = l >> 4;
  const int qsub = w & 1, ch = w >> 1;
  f32x4 acc[2] = {};
  const f16* arow = x16 + (size_t)(n0 + qsub * 16 + lq) * QD;
  #pragma unroll
  for (int ks = 0; ks < 10; ++ks) {
    f16x8 a = *reinterpret_cast<const f16x8*>(&arow[ks * 32 + lk * 8]);
    #pragma unroll
    for (int df = 0; df < 2; ++df) {
      const f16* brow = WqT + (size_t)(h * 64 + ch * 32 + df * 16 + lq) * QD;
      f16x8 b = *reinterpret_cast<const f16x8*>(&brow[ks * 32 + lk * 8]);
      acc[df] = MFMA(a, b, acc[df]);
    }
  }
  const float sc = 0.09375f * LOG2E;
  #pragma unroll
  for (int df = 0; df < 2; ++df)
    #pragma unroll
    for (int r = 0; r < 4; ++r) {
      int n = n0 + qsub * 16 + lk * 4 + r;
      int d = ch * 32 + df * 16 + lq;
      size_t idx = ((size_t)h * NTOK + n) * DH + d;
      qhat[idx] = (f16)(sc * (qinj[idx] + acc[df][r]));
    }
}

// ---------------------------------------------------------------------------
// attn_f16p: R14's kernel, byte-identical. grid 1536 = 8h x 2strm x 4sp x
// 24qt; 128-thr blocks; no-max softmax; f16 O partials.
// ---------------------------------------------------------------------------
__global__ __launch_bounds__(128, 2) void attn_f16p(
    const f16* __restrict__ qhat, const f16* __restrict__ qc16,
    const f16* __restrict__ k16,  const f16* __restrict__ kc16,
    const f16* __restrict__ vt16, const f16* __restrict__ vct16,
    f16* __restrict__ partO, float* __restrict__ partS)
{
  __shared__ __align__(16) f16 smem[2][2][2048];   // [buf][K|V][32x64 | 64x32]
  __shared__ __align__(16) f16 pbuf[2][640];       // per-wave P [16q][40]

  const int bid = blockIdx.x;
  const int h    = bid & 7;
  const int strm = (bid >> 3) & 1;
  const int sp   = (bid >> 4) & 3;
  const int qt   = bid >> 6;              // 0..23 (96 q-rows each)
  const int tid = threadIdx.x;
  const int w = tid >> 6, l = tid & 63;
  const int lq = l & 15, lk = l >> 4;
  const size_t hb = (size_t)h * NTOK * DH;
  const int row0 = qt * 96 + w * 48 + lq;   // qblock rows: +0, +16, +32

  // ---- Q fragments (B-operand, 16B contiguous per lane) ----
  f16x8 qh0[2], qh1[2], qh2[2], qc0[2], qc1[2], qc2[2];
  {
    const size_t qr0 = hb + (size_t)row0 * DH;
    #pragma unroll
    for (int ks = 0; ks < 2; ++ks) {
      const int o = ks * 32 + lk * 8;
      qc0[ks] = *reinterpret_cast<const f16x8*>(&qc16[qr0 + o]);
      qc1[ks] = *reinterpret_cast<const f16x8*>(&qc16[qr0 + 16 * DH + o]);
      qc2[ks] = *reinterpret_cast<const f16x8*>(&qc16[qr0 + 32 * DH + o]);
      if (!strm) {
        qh0[ks] = *reinterpret_cast<const f16x8*>(&qhat[qr0 + o]);
        qh1[ks] = *reinterpret_cast<const f16x8*>(&qhat[qr0 + 16 * DH + o]);
        qh2[ks] = *reinterpret_cast<const f16x8*>(&qhat[qr0 + 32 * DH + o]);
      } else { qh0[ks] = qc0[ks]; qh1[ks] = qc1[ks]; qh2[ks] = qc2[ks]; }
    }
  }

  // ---- staging geometry (linear dest + inverse-swizzled source for K) ----
  const int krow = tid >> 3;                       // 0..15 (chunk2: +16)
  const int ksw  = ((tid & 7) ^ (krow & 7)) * 8;
  const int vrow = tid >> 2;                       // 0..31 (chunk2: +32)
  const int voff = (tid & 3) * 8;
  const f16* gK = (strm ? kc16 : k16) + hb;
  const f16* gV = (strm ? vct16 : vt16) + (size_t)h * DH * NTOK;
  const int lb0 = __builtin_amdgcn_readfirstlane((tid & 64) * 8);
  const int lb1 = 1024 + lb0;

  #define STAGE(nb, j0)                                                      \
    do {                                                                     \
      GLDS(gK + (size_t)((j0) + krow) * 64 + ksw,        &smem[nb][0][lb0]); \
      GLDS(gK + (size_t)((j0) + 16 + krow) * 64 + ksw,   &smem[nb][0][lb1]); \
      GLDS(gV + (size_t)vrow * NTOK + (j0) + voff,       &smem[nb][1][lb0]); \
      GLDS(gV + (size_t)(32 + vrow) * NTOK + (j0) + voff,&smem[nb][1][lb1]); \
    } while (0)

  const int swz = (lq & 7) * 8;
  int xo[2];
  #pragma unroll
  for (int ks = 0; ks < 2; ++ks) xo[ks] = ((ks * 32 + lk * 8) ^ swz);

  float S0 = 0.f, S1 = 0.f, S2 = 0.f;            // per-lane exp-sums
  float ax0, ax1, ax2;                            // per-lane aux partials
  ax0 = ax1 = ax2 = strm ? INFINITY : -INFINITY;
  f32x4 O0[4] = {}, O1_[4] = {}, O2_[4] = {};
  f16* Pq = &pbuf[w][0];

  // no-max softmax: exp2 + per-lane sum + P round-trip -> PV B-fragment
  auto SMX = [&](const f32x4* s, float& Sl) -> f16x8 {
    float p0 = EXP2(s[0][0]), p1 = EXP2(s[0][1]);
    float p2 = EXP2(s[0][2]), p3 = EXP2(s[0][3]);
    float p4 = EXP2(s[1][0]), p5 = EXP2(s[1][1]);
    float p6 = EXP2(s[1][2]), p7 = EXP2(s[1][3]);
    Sl += ((p0 + p1) + (p2 + p3)) + ((p4 + p5) + (p6 + p7));
    uint2 wA, wB;
    wA.x = pkrtz(p0, p1); wA.y = pkrtz(p2, p3);
    wB.x = pkrtz(p4, p5); wB.y = pkrtz(p6, p7);
    *reinterpret_cast<uint2*>(Pq + lq * 40 + lk * 4)      = wA;  // keys jf0
    *reinterpret_cast<uint2*>(Pq + lq * 40 + 16 + lk * 4) = wB;  // keys jf1
    return *reinterpret_cast<const f16x8*>(Pq + lq * 40 + lk * 8);
  };

  const int jb = sp * (TPS * 32);
  STAGE(0, jb);
  asm volatile("s_waitcnt vmcnt(0)" ::: "memory");
  __builtin_amdgcn_sched_barrier(0);
  __builtin_amdgcn_s_barrier();
  __builtin_amdgcn_sched_barrier(0);

  int cur = 0;
  for (int t = 0; t < TPS; ++t) {
    if (t + 1 < TPS) STAGE(cur ^ 1, jb + (t + 1) * 32);

    const f16* Kb = &smem[cur][0][0];
    const f16* Vb = &smem[cur][1][0];

    // ---- QK^T (swapped): s[key][q], 3 qblocks share every K read ----
    f32x4 sA[2] = {}, sB[2] = {}, sC[2] = {};
    __builtin_amdgcn_s_setprio(1);
    if (!strm) {
      float m3A = -INFINITY, m3B = -INFINITY, m3C = -INFINITY;
      #pragma unroll
      for (int jf = 0; jf < 2; ++jf) {
        f32x4 tA = {}, tB = {}, tC = {};
        const int rb = (jf * 16 + lq) * 64;
        #pragma unroll
        for (int ks = 0; ks < 2; ++ks) {
          f16x8 aK = *reinterpret_cast<const f16x8*>(&Kb[rb + xo[ks]]);
          sA[jf] = MFMA(aK, qh0[ks], sA[jf]);
          sB[jf] = MFMA(aK, qh1[ks], sB[jf]);
          sC[jf] = MFMA(aK, qh2[ks], sC[jf]);
          tA = MFMA(aK, qc0[ks], tA);
          tB = MFMA(aK, qc1[ks], tB);
          tC = MFMA(aK, qc2[ks], tC);
        }
        m3A = fmaxf(m3A, fmaxf(fmaxf(tA[0], tA[1]), fmaxf(tA[2], tA[3])));
        m3B = fmaxf(m3B, fmaxf(fmaxf(tB[0], tB[1]), fmaxf(tB[2], tB[3])));
        m3C = fmaxf(m3C, fmaxf(fmaxf(tC[0], tC[1]), fmaxf(tC[2], tC[3])));
      }
      ax0 = fmaxf(ax0, m3A); ax1 = fmaxf(ax1, m3B); ax2 = fmaxf(ax2, m3C);
    } else {
      #pragma unroll
      for (int jf = 0; jf < 2; ++jf) {
        const int rb = (jf * 16 + lq) * 64;
        #pragma unroll
        for (int ks = 0; ks < 2; ++ks) {
          f16x8 aK = *reinterpret_cast<const f16x8*>(&Kb[rb + xo[ks]]);
          sA[jf] = MFMA(aK, qc0[ks], sA[jf]);
          sB[jf] = MFMA(aK, qc1[ks], sB[jf]);
          sC[jf] = MFMA(aK, qc2[ks], sC[jf]);
        }
      }
      ax0 = fminf(ax0, fminf(fminf(fminf(sA[0][0], sA[0][1]), fminf(sA[0][2], sA[0][3])),
                             fminf(fminf(sA[1][0], sA[1][1]), fminf(sA[1][2], sA[1][3]))));
      ax1 = fminf(ax1, fminf(fminf(fminf(sB[0][0], sB[0][1]), fminf(sB[0][2], sB[0][3])),
                             fminf(fminf(sB[1][0], sB[1][1]), fminf(sB[1][2], sB[1][3]))));
      ax2 = fminf(ax2, fminf(fminf(fminf(sC[0][0], sC[0][1]), fminf(sC[0][2], sC[0][3])),
                             fminf(fminf(sC[1][0], sC[1][1]), fminf(sC[1][2], sC[1][3]))));
    }
    __builtin_amdgcn_s_setprio(0);

    // ---- no-max softmax + P round-trip (no shfl, no rescale) ----
    f16x8 pbA = SMX(sA, S0);
    f16x8 pbB = SMX(sB, S1);
    f16x8 pbC = SMX(sC, S2);

    // ---- PV (swapped): O[d][q], 3 qblocks share every V read ----
    __builtin_amdgcn_s_setprio(1);
    #pragma unroll
    for (int df = 0; df < 4; ++df) {
      f16x8 aV = *reinterpret_cast<const f16x8*>(&Vb[(df * 16 + lq) * 32 + lk * 8]);
      O0[df]  = MFMA(aV, pbA, O0[df]);
      O1_[df] = MFMA(aV, pbB, O1_[df]);
      O2_[df] = MFMA(aV, pbC, O2_[df]);
    }
    __builtin_amdgcn_s_setprio(0);

    asm volatile("s_waitcnt vmcnt(0)" ::: "memory");
    __builtin_amdgcn_sched_barrier(0);
    __builtin_amdgcn_s_barrier();
    __builtin_amdgcn_sched_barrier(0);
    cur ^= 1;
  }

  // ---- final per-lane -> per-row reductions, then f16 partial store ----
  S0 += __shfl_xor(S0, 16); S0 += __shfl_xor(S0, 32);
  S1 += __shfl_xor(S1, 16); S1 += __shfl_xor(S1, 32);
  S2 += __shfl_xor(S2, 16); S2 += __shfl_xor(S2, 32);
  if (!strm) {
    ax0 = fmaxf(ax0, __shfl_xor(ax0, 16)); ax0 = fmaxf(ax0, __shfl_xor(ax0, 32));
    ax1 = fmaxf(ax1, __shfl_xor(ax1, 16)); ax1 = fmaxf(ax1, __shfl_xor(ax1, 32));
    ax2 = fmaxf(ax2, __shfl_xor(ax2, 16)); ax2 = fmaxf(ax2, __shfl_xor(ax2, 32));
  } else {
    ax0 = fminf(ax0, __shfl_xor(ax0, 16)); ax0 = fminf(ax0, __shfl_xor(ax0, 32));
    ax1 = fminf(ax1, __shfl_xor(ax1, 16)); ax1 = fminf(ax1, __shfl_xor(ax1, 32));
    ax2 = fminf(ax2, __shfl_xor(ax2, 16)); ax2 = fminf(ax2, __shfl_xor(ax2, 32));
  }
  {
    const size_t u = (size_t)((strm * NSPLIT + sp) * 8 + h);
    f16* p0 = partO + (u * NTOK + (size_t)row0) * 64;
    f16* p1 = p0 + (size_t)16 * 64;
    f16* p2 = p0 + (size_t)32 * 64;
    #pragma unroll
    for (int df = 0; df < 4; ++df) {
      uint2 w0, w1, w2;
      w0.x = pkrtz(O0[df][0],  O0[df][1]);  w0.y = pkrtz(O0[df][2],  O0[df][3]);
      w1.x = pkrtz(O1_[df][0], O1_[df][1]); w1.y = pkrtz(O1_[df][2], O1_[df][3]);
      w2.x = pkrtz(O2_[df][0], O2_[df][1]); w2.y = pkrtz(O2_[df][2], O2_[df][3]);
      *reinterpret_cast<uint2*>(p0 + df * 16 + lk * 4) = w0;
      *reinterpret_cast<uint2*>(p1 + df * 16 + lk * 4) = w1;
      *reinterpret_cast<uint2*>(p2 + df * 16 + lk * 4) = w2;
    }
    if (lk == 0) {
      float* s0 = partS + (u * NTOK + (size_t)row0) * 2;
      s0[0] = S0; s0[1] = ax0;
      s0[32] = S1; s0[33] = ax1;     // row0+16 -> offset 16*2
      s0[64] = S2; s0[65] = ax2;     // row0+32 -> offset 32*2
    }
  }
  #undef STAGE
}

// ---------------------------------------------------------------------------
// merge8: sum 4 splits x 2 streams (f16 O partials, linear), gvm, write mid.
// grid 288 (1D): h = bid&7 pins each head's merge to the XCD whose L2 holds
// its partials (attn uses the same h = bid&7 mapping). 256 thr =
// (row 0..63) x (16-d segment 0..3).
// ---------------------------------------------------------------------------
__global__ __launch_bounds__(256) void merge8(
    const f16* __restrict__ partO, const float* __restrict__ partS,
    const float* __restrict__ mask, f16* __restrict__ mid)
{
  const int h = blockIdx.x & 7, qt = blockIdx.x >> 3;
  const int tid = threadIdx.x;
  const int r = tid >> 2, ds = (tid & 3) * 16;
  const int n = qt * 64 + r;

  float S1 = 0.f, S2 = 0.f, mx = -INFINITY, mn = INFINITY;
  #pragma unroll
  for (int s = 0; s < NSPLIT; ++s) {
    const float* a = partS + ((size_t)((0 * NSPLIT + s) * 8 + h) * NTOK + n) * 2;
    const float* b = partS + ((size_t)((1 * NSPLIT + s) * 8 + h) * NTOK + n) * 2;
    S1 += a[0]; mx = fmaxf(mx, a[1]);
    S2 += b[0]; mn = fminf(mn, b[1]);
  }

  float mv = mask[n];
  float mm = (mv < 0.5f) ? 1.0f : (mv > 0.5f ? -1.0f : -mv);
  float gvm = (mn - mx * LOG2E) * mm;          // exp2 domain
  float A1 = gvm;
  float Mf = fmaxf(A1, 0.0f);
  float w1 = exp2f(A1 - Mf), w2 = exp2f(-Mf);
  float inv = 1.0f / (w1 * S1 + w2 * S2);

  float o1[16] = {}, o2[16] = {};
  #pragma unroll
  for (int s = 0; s < NSPLIT; ++s) {
    const f16* a = partO + ((size_t)((0 * NSPLIT + s) * 8 + h) * NTOK + n) * 64 + ds;
    const f16* b = partO + ((size_t)((1 * NSPLIT + s) * 8 + h) * NTOK + n) * 64 + ds;
    f16x8 a0 = *reinterpret_cast<const f16x8*>(a);
    f16x8 a1 = *reinterpret_cast<const f16x8*>(a + 8);
    f16x8 b0 = *reinterpret_cast<const f16x8*>(b);
    f16x8 b1 = *reinterpret_cast<const f16x8*>(b + 8);
    #pragma unroll
    for (int j = 0; j < 8; ++j) {
      o1[j]     += (float)a0[j];
      o1[8 + j] += (float)a1[j];
      o2[j]     += (float)b0[j];
      o2[8 + j] += (float)b1[j];
    }
  }
  f16 ov[16];
  #pragma unroll
  for (int j = 0; j < 16; ++j)
    ov[j] = (f16)((w1 * o1[j] + w2 * o2[j]) * inv);
  f16* dst = mid + (size_t)n * INNER + h * 64 + ds;
  *reinterpret_cast<f16x8*>(dst)     = *reinterpret_cast<f16x8*>(&ov[0]);
  *reinterpret_cast<f16x8*>(dst + 8) = *reinterpret_cast<f16x8*>(&ov[8]);
}

// ---------------------------------------------------------------------------
// out_mfma: out = mid(f16) @ Wo + bo.  grid (144, 5), 64 threads (1 wave).
// ---------------------------------------------------------------------------
__global__ __launch_bounds__(64) void out_mfma(
    const f16* __restrict__ mid, const f16* __restrict__ WoT,
    const float* __restrict__ bo, float* __restrict__ out)
{
  const int n0 = blockIdx.x * 16;
  const int o0 = blockIdx.y * 64;
  const int l = threadIdx.x, lq = l & 15, lk = l >> 4;
  f32x4 acc[4] = {};
  const f16* arow = mid + (size_t)(n0 + lq) * INNER;
  #pragma unroll
  for (int ks = 0; ks < 16; ++ks) {
    f16x8 a = *reinterpret_cast<const f16x8*>(&arow[ks * 32 + lk * 8]);
    #pragma unroll
    for (int df = 0; df < 4; ++df) {
      f16x8 b = *reinterpret_cast<const f16x8*>(
          &WoT[(size_t)(o0 + df * 16 + lq) * INNER + ks * 32 + lk * 8]);
      acc[df] = MFMA(a, b, acc[df]);
    }
  }
  #pragma unroll
  for (int df = 0; df < 4; ++df) {
    float bb = bo[o0 + df * 16 + lq];
    #pragma unroll
    for (int r = 0; r < 4; ++r) {
      int n = n0 + lk * 4 + r;
      out[(size_t)n * QD + o0 + df * 16 + lq] = acc[df][r] + bb;
    }
  }
}

// ---------------------------------------------------------------------------
extern "C" void kernel_launch(void* const* d_in, const int* in_sizes, int n_in,
                              void* d_out, int out_size, void* d_ws, size_t ws_size,
                              hipStream_t stream) {
  const float* x    = (const float*)d_in[0];
  const float* Wq   = (const float*)d_in[1];
  const float* Wo   = (const float*)d_in[2];
  const float* bo   = (const float*)d_in[3];
  const float* qinj = (const float*)d_in[4];
  const float* kinj = (const float*)d_in[5];
  const float* vinj = (const float*)d_in[6];
  const float* kcnt = (const float*)d_in[7];
  const float* vcnt = (const float*)d_in[8];
  const float* mask = (const float*)d_in[9];
  float* out = (float*)d_out;

  const size_t T = (size_t)HEADS * NTOK * DH;   // 1179648
  f16* qhat = (f16*)d_ws;
  f16* qc16 = qhat + T;
  f16* k16  = qc16 + T;
  f16* kc16 = k16  + T;
  f16* vt16 = kc16 + T;
  f16* vct16= vt16 + T;
  f16* mid  = vct16 + T;                 // [2304][512] f16
  f16* x16  = mid;                       // aliased: dead before merge8 writes mid
  f16* WqT  = mid + 737280;
  f16* WoT  = mid + T;
  f16* partO = WoT + 163840;             // 64u x 2304 x 64 f16 (~19 MB)
  float* partS = (float*)(partO + (size_t)64 * NTOK * 64);  // 64u x 2304 x 2 f32

  prep_all   <<<2744, 256, 0, stream>>>(qinj, kinj, kcnt, x, vinj, vcnt, Wq, Wo,
                                        qc16, k16, kc16, x16, vt16, vct16, WqT, WoT);
  qblend_mfma<<<dim3(72, 8), 256, 0, stream>>>(x16, WqT, qinj, qhat);
  attn_f16p  <<<1536, 128, 0, stream>>>(qhat, qc16, k16, kc16, vt16, vct16,
                                        partO, partS);
  merge8     <<<288, 256, 0, stream>>>(partO, partS, mask, mid);
  out_mfma   <<<dim3(144, 5), 64, 0, stream>>>(mid, WoT, bo, out);
}